// Round 8
// baseline (261.756 us; speedup 1.0000x reference)
//
#include <hip/hip_runtime.h>
#include <hip/hip_bf16.h>

// MyGNN on MI355X — round 13 (= round 12 with the sign-extension fix).
//  prep: zero counts + W1/Wfi -> frag bf16 + Wc=W2@Wl -> frag bf16 + bc
//  K1 (fused): single-pass WIDE fill (1 edge/thread, device atomicAdd counts,
//              plain write-back bucket stores) ∪ gemm1(x1@W1->t_bf)
//              ∪ branch0(gather x0@Wfi->out)
//  agg1: h1 = A@t1 + b1 (bf16 out)     [2 rows/wave, uint2 half-wave gathers]
//  agg2_sel: sel[m] = A-row(node(m)) @ h1   (M rows, bf16 out, no bias)
//  br1: out1 = sel@Wc + bc            [gemm2 eliminated algebraically]
// Round-13 fix: round 12 crashed because SLOT_C did `(int)shfl >> 16`
// (arithmetic shift) — slot ids >= 32768 sign-extended negative -> OOB gather.
// Extraction is now unsigned-shift + mask. Everything else identical to round
// 12 so the round-11 -> round-13 delta isolates the 2-rows/wave aggregate.

#define B_    64
#define ADJ_  1000
#define N_    64000
#define E_    (1 << 20)
#define M_    32000
#define DV    128
#define CAP   64
#define CHUNKS 4096
#define EPB   (E_ / CHUNKS)    // 256 edges per fill block = 1/thread
#define AGUNROLL 24            // agg gather unroll depth (P(cnt>24) ~ 2%)

typedef __attribute__((ext_vector_type(8))) short short8v;   // 8 bf16
typedef __attribute__((ext_vector_type(4))) float float4v;

__device__ __forceinline__ float u2f(unsigned int u) {
  union { unsigned int i; float f; } x; x.i = u; return x.f;
}
__device__ __forceinline__ unsigned short f2bf(float f) {   // RNE
  union { float f; unsigned int i; } x; x.f = f;
  unsigned int r = x.i + 0x7fffu + ((x.i >> 16) & 1u);
  return (unsigned short)(r >> 16);
}
__device__ __forceinline__ unsigned int pack_bf2(float a, float b) {
  __hip_bfloat162 h = __float22bfloat162_rn(float2{a, b});
  union { __hip_bfloat162 h; unsigned int u; } c; c.h = h;
  return c.u;
}

// frag addr for W[k][n] (128x128), matches gemm_tile's B-frag read
__device__ __forceinline__ int frag_addr(int k, int n) {
  return ((((n >> 4) * 4 + (k >> 5)) * 64 + ((k >> 3) & 3) * 16 + (n & 15)) << 3)
       + (k & 7);
}

// ---------------- prep: counts=0 + W frags + Wc fold ----------------
// blocks 0-15: W1/Wfi frag convert; 16-31: Wc=W2@Wl fold; 32: bc. Grid 33.
__global__ __launch_bounds__(256)
void prep_k(const float* __restrict__ W1, const float* __restrict__ Wfi,
            const float* __restrict__ W2, const float* __restrict__ Wl,
            const float* __restrict__ b2, const float* __restrict__ bl,
            unsigned short* __restrict__ Wbf, float* __restrict__ bc,
            int* __restrict__ counts) {
  int b = blockIdx.x, t = threadIdx.x;
  if (b < 16) {
    const float* W = (b < 8) ? W1 : Wfi;
    unsigned short* out = Wbf + ((b < 8) ? 0 : 16384);
    int base = (b & 7) * 2048 + t * 8;
    float4 f0 = *(const float4*)(W + base);
    float4 f1 = *(const float4*)(W + base + 4);
    float v[8] = {f0.x, f0.y, f0.z, f0.w, f1.x, f1.y, f1.z, f1.w};
#pragma unroll
    for (int u = 0; u < 8; u++) {
      int g = base + u;
      out[frag_addr(g >> 7, g & 127)] = f2bf(v[u]);
    }
  } else if (b < 32) {
    // Wc[k][n..n+3] = sum_j W2[k][j] * Wl[j][n..n+3]
    unsigned short* out = Wbf + 2 * 16384;
    int g0 = (b - 16) * 1024 + t * 4;
    int k = g0 >> 7, n = g0 & 127;
    float4 acc = {0.f, 0.f, 0.f, 0.f};
    for (int j = 0; j < 128; j++) {
      float w2 = W2[k * 128 + j];
      float4 wl = *(const float4*)(Wl + j * 128 + n);
      acc.x += w2 * wl.x; acc.y += w2 * wl.y;
      acc.z += w2 * wl.z; acc.w += w2 * wl.w;
    }
    out[frag_addr(k, n + 0)] = f2bf(acc.x);
    out[frag_addr(k, n + 1)] = f2bf(acc.y);
    out[frag_addr(k, n + 2)] = f2bf(acc.z);
    out[frag_addr(k, n + 3)] = f2bf(acc.w);
  } else {
    if (t < 128) {
      float acc = bl[t];
      for (int k = 0; k < 128; k++) acc += b2[k] * Wl[k * 128 + t];
      bc[t] = acc;
    }
  }
  for (int i = b * 256 + t; i < N_; i += 33 * 256) counts[i] = 0;
}

// ---------------- single-pass WIDE fill (device fn): chunk c, 1 edge/thread ----------------
__device__ __forceinline__ void fill_once(const int* __restrict__ ei,
                                          int* __restrict__ counts,
                                          unsigned short* __restrict__ bucket,
                                          int c) {
  int e = c * EPB + (int)threadIdx.x;
  int d = ei[E_ + e];                    // dst
  int s = ei[e];                         // src
  int pos = atomicAdd(&counts[d], 1);    // device-scope RMW (unique slot)
  if (pos < CAP)
    bucket[(size_t)d * CAP + pos] = (unsigned short)s;   // plain write-back store
}

// ---------------- MFMA GEMM tile (device fn) ----------------
// tile = 64 rows; 4 waves x 16-row stripes; B pre-converted frag-ordered bf16.
// Two-half staging: 16 KB LDS; half-1 global loads overlap half-0 MFMAs.
// C/D: col = lane&15, row = (lane>>4)*4 + reg.
template<bool GATHER, bool ABF16, bool OUTBF16, bool HASBIAS>
__device__ __forceinline__ void gemm_tile(const void* __restrict__ in,
                                          const unsigned short* __restrict__ Wbf,
                                          const float* __restrict__ bias,
                                          void* __restrict__ out_, int tile,
                                          const int* __restrict__ bidx,
                                          const int* __restrict__ nidx,
                                          unsigned short* __restrict__ Bs) {
  int tid  = threadIdx.x;
  int lane = tid & 63;
  int wv   = tid >> 6;
  int m    = lane & 15;
  int q    = lane >> 4;
  int rbase = tile * 64 + wv * 16;
  int r     = rbase + m;

  const short8v* Wv  = (const short8v*)Wbf;   // 2048 vecs (32 KB)
  short8v*       Bsv = (short8v*)Bs;          // 1024 vecs (16 KB)

  short8v w[4];
#pragma unroll
  for (int i = 0; i < 4; i++) w[i] = Wv[tid + i * 256];

  size_t ir;
  if (GATHER) ir = (size_t)bidx[r] * ADJ_ + nidx[r];
  else        ir = (size_t)r;

  short8v af[4];
  if (ABF16) {
    const unsigned short* arow = (const unsigned short*)in + ir * DV;
#pragma unroll
    for (int kc = 0; kc < 4; kc++)
      af[kc] = *(const short8v*)(arow + kc * 32 + q * 8);
  } else {
    const float* arow = (const float*)in + ir * DV;
#pragma unroll
    for (int kc = 0; kc < 4; kc++) {
      const float4* p = (const float4*)(arow + kc * 32 + q * 8);
      float4 f0 = p[0], f1 = p[1];
      union { short8v s; unsigned int u[4]; } t;
      t.u[0] = pack_bf2(f0.x, f0.y);
      t.u[1] = pack_bf2(f0.z, f0.w);
      t.u[2] = pack_bf2(f1.x, f1.y);
      t.u[3] = pack_bf2(f1.z, f1.w);
      af[kc] = t.s;
    }
  }

#pragma unroll
  for (int i = 0; i < 4; i++) Bsv[tid + i * 256] = w[i];
  __syncthreads();

  float4v acc[8];
#pragma unroll
  for (int nb = 0; nb < 8; nb++) acc[nb] = (float4v){0.f, 0.f, 0.f, 0.f};

#pragma unroll
  for (int i = 0; i < 4; i++) w[i] = Wv[1024 + tid + i * 256];

#pragma unroll
  for (int nb = 0; nb < 4; nb++)
#pragma unroll
    for (int kc = 0; kc < 4; kc++) {
      short8v bf = Bsv[(nb * 4 + kc) * 64 + lane];
      acc[nb] = __builtin_amdgcn_mfma_f32_16x16x32_bf16(af[kc], bf, acc[nb], 0, 0, 0);
    }
  __syncthreads();
#pragma unroll
  for (int i = 0; i < 4; i++) Bsv[tid + i * 256] = w[i];
  __syncthreads();
#pragma unroll
  for (int nb = 4; nb < 8; nb++)
#pragma unroll
    for (int kc = 0; kc < 4; kc++) {
      short8v bf = Bsv[((nb - 4) * 4 + kc) * 64 + lane];
      acc[nb] = __builtin_amdgcn_mfma_f32_16x16x32_bf16(af[kc], bf, acc[nb], 0, 0, 0);
    }

#pragma unroll
  for (int nb = 0; nb < 8; nb++) {
    float bvn = HASBIAS ? bias[nb * 16 + m] : 0.f;
    int col = nb * 16 + m;
#pragma unroll
    for (int i = 0; i < 4; i++) {
      int row = rbase + q * 4 + i;
      float v = acc[nb][i] + bvn;
      if (OUTBF16) ((unsigned short*)out_)[(size_t)row * DV + col] = f2bf(v);
      else         ((float*)out_)[(size_t)row * DV + col] = v;
    }
  }
}

// ---------------- K1: fused wide fill + gemm1 + branch0 ----------------
// Period-11 blocks: rem 0..7 -> fill chunk g*8+rem (4096 fills); rem 8..10 ->
// o = g*3+rem-8: o<1000 gemm1, o<1500 br0, else idle. Grid 512*11 = 5632.
__global__ __launch_bounds__(256)
void k1_fused(const int* __restrict__ ei, int* __restrict__ counts,
              unsigned short* __restrict__ bucket,
              const float* __restrict__ x1, const unsigned short* __restrict__ Wbf,
              unsigned int* __restrict__ t_bf,
              const float* __restrict__ x0, const float* __restrict__ bfi,
              float* __restrict__ out0,
              const int* __restrict__ b0, const int* __restrict__ n0i) {
  __shared__ unsigned short Bs[8192];   // 16 KB
  int g = blockIdx.x / 11, rem = blockIdx.x % 11;
  if (rem < 8) { fill_once(ei, counts, bucket, g * 8 + rem); return; }
  int o = g * 3 + rem - 8;
  if (o < 1000)
    gemm_tile<false, false, true, false>(x1, Wbf, nullptr, t_bf, o, nullptr, nullptr, Bs);
  else if (o < 1500)
    gemm_tile<true, false, false, true>(x0, Wbf + 16384, bfi, out0, o - 1000, b0, n0i, Bs);
}

// ---------------- standalone GEMM ----------------
template<bool GATHER, bool ABF16, bool OUTBF16, bool HASBIAS>
__global__ __launch_bounds__(256)
void gemm_k(const void* __restrict__ in, const unsigned short* __restrict__ Wbf,
            const float* __restrict__ bias, void* __restrict__ out_,
            const int* __restrict__ bidx, const int* __restrict__ nidx) {
  __shared__ unsigned short Bs[8192];
  gemm_tile<GATHER, ABF16, OUTBF16, HASBIAS>(in, Wbf, bias, out_, blockIdx.x, bidx, nidx, Bs);
}

// ---------------- aggregation: TWO rows per wave ----------------
// Lanes 0-31 serve row rA = 2*wave, lanes 32-63 row rB = 2*wave+1 (per-lane
// gather addresses). Each lane covers 8B (uint2) of its row: 32 lanes x 8B =
// 256B/row. Slots: bucket row (64 ushorts) read as 32 uints, one per lane.
// Slot i of my half's row: uint from lane (i>>1)|(lane&32), half i&1 —
// extracted with UNSIGNED shift+mask (round-12 bug: arithmetic >>16 sign-
// extended slot ids >= 32768 -> OOB). cnt is half-uniform.
template<bool OUTBF16, bool SEL>
__global__ __launch_bounds__(256)
void aggregate_k(const uint2* __restrict__ x,        // bf16 rows as 32 x uint2
                 const int* __restrict__ counts,
                 const unsigned int* __restrict__ bucket,  // rows of 32 uints
                 const float* __restrict__ bias, void* __restrict__ out_,
                 const int* __restrict__ bidx, const int* __restrict__ nidx) {
  int wave = (blockIdx.x * 256 + threadIdx.x) >> 6;
  int lane = threadIdx.x & 63;
  int l5   = lane & 31;
  int r    = wave * 2 + (lane >> 5);                 // my half's row
  int node = SEL ? (bidx[r] * ADJ_ + nidx[r]) : r;
  int cnt  = counts[node]; cnt = min(cnt, CAP);      // half-uniform
  unsigned int mp = bucket[node * 32 + l5];          // slots 2*l5, 2*l5+1

  float4 acc;
  if (bias) acc = ((const float4*)bias)[l5];
  else      acc = float4{0.f, 0.f, 0.f, 0.f};

  // unsigned extract: shfl as int, reinterpret unsigned, logical shift + mask
#define SLOT_C(i)                                                            \
  ((int)((((unsigned int)__shfl((int)mp, ((i) >> 1) | (lane & 32), 64))      \
          >> (((i) & 1) * 16)) & 0xffffu))

  uint2 uu[AGUNROLL];
#pragma unroll
  for (int i = 0; i < AGUNROLL; i++)
    if (i < cnt) {                                   // half-uniform guard
      int s = SLOT_C(i);
      uu[i] = x[(size_t)s * 32 + l5];
    }
#pragma unroll
  for (int i = 0; i < AGUNROLL; i++)
    if (i < cnt) {
      acc.x += u2f(uu[i].x << 16);
      acc.y += u2f(uu[i].x & 0xffff0000u);
      acc.z += u2f(uu[i].y << 16);
      acc.w += u2f(uu[i].y & 0xffff0000u);
    }
  for (int d = AGUNROLL; d < cnt; d++) {             // rare tail (~2% of rows)
    unsigned int v = (unsigned int)__shfl((int)mp, (d >> 1) | (lane & 32), 64);
    int s = (int)((v >> ((d & 1) * 16)) & 0xffffu);
    uint2 u = x[(size_t)s * 32 + l5];
    acc.x += u2f(u.x << 16);
    acc.y += u2f(u.x & 0xffff0000u);
    acc.z += u2f(u.y << 16);
    acc.w += u2f(u.y & 0xffff0000u);
  }
#undef SLOT_C

  if (OUTBF16) {
    uint2 p; p.x = pack_bf2(acc.x, acc.y); p.y = pack_bf2(acc.z, acc.w);
    ((uint2*)out_)[(size_t)r * 32 + l5] = p;
  } else {
    ((float4*)out_)[(size_t)r * 32 + l5] = acc;
  }
}

extern "C" void kernel_launch(void* const* d_in, const int* in_sizes, int n_in,
                              void* d_out, int out_size, void* d_ws, size_t ws_size,
                              hipStream_t stream) {
  const float* x0  = (const float*)d_in[0];
  const float* x1  = (const float*)d_in[1];
  const int*   ei  = (const int*)  d_in[2];
  const int*   b0  = (const int*)  d_in[3];
  const int*   n0i = (const int*)  d_in[4];
  const int*   b1  = (const int*)  d_in[5];
  const int*   n1i = (const int*)  d_in[6];
  const float* W1  = (const float*)d_in[7];
  const float* bb1 = (const float*)d_in[8];
  const float* W2  = (const float*)d_in[9];
  const float* bb2 = (const float*)d_in[10];
  const float* Wl  = (const float*)d_in[11];
  const float* bl  = (const float*)d_in[12];
  const float* Wfi = (const float*)d_in[13];
  const float* bfi = (const float*)d_in[14];
  float* out = (float*)d_out;

  // ws: t_bf 16MB (sel_bf aliases it) | h_bf 16MB | counts 0.25MB | bucket 8MB
  //     | Wbf 96KB | bc 512B   (total ~40.4MB)
  unsigned int*   t_bf   = (unsigned int*)d_ws;
  unsigned int*   sel_bf = t_bf;                        // alias: t1 dead after agg1
  unsigned int*   h_bf   = t_bf + (size_t)N_ * 64;
  int*            counts = (int*)(h_bf + (size_t)N_ * 64);
  unsigned short* bucket = (unsigned short*)(counts + N_);
  unsigned short* Wbf    = bucket + (size_t)N_ * CAP;
  float*          bc     = (float*)(Wbf + 3 * 16384);

  // prep: counts=0, W1/Wfi frag, Wc=W2@Wl frag, bc=b2@Wl+bl
  prep_k<<<33, 256, 0, stream>>>(W1, Wfi, W2, Wl, bb2, bl, Wbf, bc, counts);

  // K1: wide single-pass fill ∪ t1=x1@W1 ∪ out0=gather(x0)@Wfi+bfi
  k1_fused<<<5632, 256, 0, stream>>>(ei, counts, bucket, x1, Wbf, t_bf,
                                     x0, bfi, out, b0, n0i);

  // h1 = A@t1 + b1  (bf16 out)  — 2 rows/wave: N/8 blocks
  aggregate_k<true, false><<<N_ / 8, 256, 0, stream>>>((const uint2*)t_bf, counts,
                                                       (const unsigned int*)bucket,
                                                       bb1, h_bf, nullptr, nullptr);
  // sel[m] = A-row(node(m)) @ h1  (bf16 out, bias folded into bc) — M/8 blocks
  aggregate_k<true, true><<<M_ / 8, 256, 0, stream>>>((const uint2*)h_bf, counts,
                                                      (const unsigned int*)bucket,
                                                      nullptr, sel_bf, b1, n1i);
  // out1 = sel@Wc + bc  (f32 out)   [Wc = W2@Wl, bc = b2@Wl + bl]
  gemm_k<false, true, false, true><<<M_ / 64, 256, 0, stream>>>(sel_bf, Wbf + 2 * 16384,
                                                                bc, out + (size_t)M_ * DV,
                                                                nullptr, nullptr);
}

// Round 9
// 261.614 us; speedup vs baseline: 1.0005x; 1.0005x over previous
//
#include <hip/hip_runtime.h>
#include <hip/hip_bf16.h>

// MyGNN on MI355X — round 14.
//  prep: zero counts + W1/Wfi -> frag bf16 + Wc=W2@Wl -> frag bf16 + bc
//  K1 (fused): single-pass WIDE fill ∪ gemm1(x1@W1->t_bf) ∪ branch0(x0@Wfi->out)
//  agg1: h1 = A@t1 + b1 (bf16 out)     [2 rows/wave, uint2 half-wave gathers]
//  aggmm (NEW): out1[m] = (A-row(node(m)) @ h1) @ Wc + bc — agg2+br1 FUSED.
//    Gather accumulates directly in MFMA A-frag layout: lane (m,q) owns dims
//    {kc*32+q*8+j} of row m (4x uint4 per slot), so the f32 accumulator packs
//    straight into af[kc] with no LDS transpose. Deletes the br1 dispatch and
//    the 8MB sel materialization + re-read.
// Rounds 12/13 showed aggregate time is invariant to VMEM instruction count
// (issue-bound theory refuted twice) -> attack serial stages + traffic instead.

#define B_    64
#define ADJ_  1000
#define N_    64000
#define E_    (1 << 20)
#define M_    32000
#define DV    128
#define CAP   64
#define CHUNKS 4096
#define EPB   (E_ / CHUNKS)    // 256 edges per fill block = 1/thread
#define AGUNROLL 24            // agg gather unroll depth (P(cnt>24) ~ 2%)

typedef __attribute__((ext_vector_type(8))) short short8v;   // 8 bf16
typedef __attribute__((ext_vector_type(4))) float float4v;

__device__ __forceinline__ float u2f(unsigned int u) {
  union { unsigned int i; float f; } x; x.i = u; return x.f;
}
__device__ __forceinline__ unsigned short f2bf(float f) {   // RNE
  union { float f; unsigned int i; } x; x.f = f;
  unsigned int r = x.i + 0x7fffu + ((x.i >> 16) & 1u);
  return (unsigned short)(r >> 16);
}
__device__ __forceinline__ unsigned int pack_bf2(float a, float b) {
  __hip_bfloat162 h = __float22bfloat162_rn(float2{a, b});
  union { __hip_bfloat162 h; unsigned int u; } c; c.h = h;
  return c.u;
}

// frag addr for W[k][n] (128x128), matches the B-frag read
__device__ __forceinline__ int frag_addr(int k, int n) {
  return ((((n >> 4) * 4 + (k >> 5)) * 64 + ((k >> 3) & 3) * 16 + (n & 15)) << 3)
       + (k & 7);
}

// ---------------- prep: counts=0 + W frags + Wc fold ----------------
__global__ __launch_bounds__(256)
void prep_k(const float* __restrict__ W1, const float* __restrict__ Wfi,
            const float* __restrict__ W2, const float* __restrict__ Wl,
            const float* __restrict__ b2, const float* __restrict__ bl,
            unsigned short* __restrict__ Wbf, float* __restrict__ bc,
            int* __restrict__ counts) {
  int b = blockIdx.x, t = threadIdx.x;
  if (b < 16) {
    const float* W = (b < 8) ? W1 : Wfi;
    unsigned short* out = Wbf + ((b < 8) ? 0 : 16384);
    int base = (b & 7) * 2048 + t * 8;
    float4 f0 = *(const float4*)(W + base);
    float4 f1 = *(const float4*)(W + base + 4);
    float v[8] = {f0.x, f0.y, f0.z, f0.w, f1.x, f1.y, f1.z, f1.w};
#pragma unroll
    for (int u = 0; u < 8; u++) {
      int g = base + u;
      out[frag_addr(g >> 7, g & 127)] = f2bf(v[u]);
    }
  } else if (b < 32) {
    // Wc[k][n..n+3] = sum_j W2[k][j] * Wl[j][n..n+3]
    unsigned short* out = Wbf + 2 * 16384;
    int g0 = (b - 16) * 1024 + t * 4;
    int k = g0 >> 7, n = g0 & 127;
    float4 acc = {0.f, 0.f, 0.f, 0.f};
    for (int j = 0; j < 128; j++) {
      float w2 = W2[k * 128 + j];
      float4 wl = *(const float4*)(Wl + j * 128 + n);
      acc.x += w2 * wl.x; acc.y += w2 * wl.y;
      acc.z += w2 * wl.z; acc.w += w2 * wl.w;
    }
    out[frag_addr(k, n + 0)] = f2bf(acc.x);
    out[frag_addr(k, n + 1)] = f2bf(acc.y);
    out[frag_addr(k, n + 2)] = f2bf(acc.z);
    out[frag_addr(k, n + 3)] = f2bf(acc.w);
  } else {
    if (t < 128) {
      float acc = bl[t];
      for (int k = 0; k < 128; k++) acc += b2[k] * Wl[k * 128 + t];
      bc[t] = acc;
    }
  }
  for (int i = b * 256 + t; i < N_; i += 33 * 256) counts[i] = 0;
}

// ---------------- single-pass WIDE fill (device fn): chunk c, 1 edge/thread ----------------
__device__ __forceinline__ void fill_once(const int* __restrict__ ei,
                                          int* __restrict__ counts,
                                          unsigned short* __restrict__ bucket,
                                          int c) {
  int e = c * EPB + (int)threadIdx.x;
  int d = ei[E_ + e];                    // dst
  int s = ei[e];                         // src
  int pos = atomicAdd(&counts[d], 1);    // device-scope RMW (unique slot)
  if (pos < CAP)
    bucket[(size_t)d * CAP + pos] = (unsigned short)s;   // plain write-back store
}

// ---------------- MFMA GEMM tile (device fn) ----------------
template<bool GATHER, bool ABF16, bool OUTBF16, bool HASBIAS>
__device__ __forceinline__ void gemm_tile(const void* __restrict__ in,
                                          const unsigned short* __restrict__ Wbf,
                                          const float* __restrict__ bias,
                                          void* __restrict__ out_, int tile,
                                          const int* __restrict__ bidx,
                                          const int* __restrict__ nidx,
                                          unsigned short* __restrict__ Bs) {
  int tid  = threadIdx.x;
  int lane = tid & 63;
  int wv   = tid >> 6;
  int m    = lane & 15;
  int q    = lane >> 4;
  int rbase = tile * 64 + wv * 16;
  int r     = rbase + m;

  const short8v* Wv  = (const short8v*)Wbf;   // 2048 vecs (32 KB)
  short8v*       Bsv = (short8v*)Bs;          // 1024 vecs (16 KB)

  short8v w[4];
#pragma unroll
  for (int i = 0; i < 4; i++) w[i] = Wv[tid + i * 256];

  size_t ir;
  if (GATHER) ir = (size_t)bidx[r] * ADJ_ + nidx[r];
  else        ir = (size_t)r;

  short8v af[4];
  if (ABF16) {
    const unsigned short* arow = (const unsigned short*)in + ir * DV;
#pragma unroll
    for (int kc = 0; kc < 4; kc++)
      af[kc] = *(const short8v*)(arow + kc * 32 + q * 8);
  } else {
    const float* arow = (const float*)in + ir * DV;
#pragma unroll
    for (int kc = 0; kc < 4; kc++) {
      const float4* p = (const float4*)(arow + kc * 32 + q * 8);
      float4 f0 = p[0], f1 = p[1];
      union { short8v s; unsigned int u[4]; } t;
      t.u[0] = pack_bf2(f0.x, f0.y);
      t.u[1] = pack_bf2(f0.z, f0.w);
      t.u[2] = pack_bf2(f1.x, f1.y);
      t.u[3] = pack_bf2(f1.z, f1.w);
      af[kc] = t.s;
    }
  }

#pragma unroll
  for (int i = 0; i < 4; i++) Bsv[tid + i * 256] = w[i];
  __syncthreads();

  float4v acc[8];
#pragma unroll
  for (int nb = 0; nb < 8; nb++) acc[nb] = (float4v){0.f, 0.f, 0.f, 0.f};

#pragma unroll
  for (int i = 0; i < 4; i++) w[i] = Wv[1024 + tid + i * 256];

#pragma unroll
  for (int nb = 0; nb < 4; nb++)
#pragma unroll
    for (int kc = 0; kc < 4; kc++) {
      short8v bf = Bsv[(nb * 4 + kc) * 64 + lane];
      acc[nb] = __builtin_amdgcn_mfma_f32_16x16x32_bf16(af[kc], bf, acc[nb], 0, 0, 0);
    }
  __syncthreads();
#pragma unroll
  for (int i = 0; i < 4; i++) Bsv[tid + i * 256] = w[i];
  __syncthreads();
#pragma unroll
  for (int nb = 4; nb < 8; nb++)
#pragma unroll
    for (int kc = 0; kc < 4; kc++) {
      short8v bf = Bsv[((nb - 4) * 4 + kc) * 64 + lane];
      acc[nb] = __builtin_amdgcn_mfma_f32_16x16x32_bf16(af[kc], bf, acc[nb], 0, 0, 0);
    }

#pragma unroll
  for (int nb = 0; nb < 8; nb++) {
    float bvn = HASBIAS ? bias[nb * 16 + m] : 0.f;
    int col = nb * 16 + m;
#pragma unroll
    for (int i = 0; i < 4; i++) {
      int row = rbase + q * 4 + i;
      float v = acc[nb][i] + bvn;
      if (OUTBF16) ((unsigned short*)out_)[(size_t)row * DV + col] = f2bf(v);
      else         ((float*)out_)[(size_t)row * DV + col] = v;
    }
  }
}

// ---------------- K1: fused wide fill + gemm1 + branch0 ----------------
__global__ __launch_bounds__(256)
void k1_fused(const int* __restrict__ ei, int* __restrict__ counts,
              unsigned short* __restrict__ bucket,
              const float* __restrict__ x1, const unsigned short* __restrict__ Wbf,
              unsigned int* __restrict__ t_bf,
              const float* __restrict__ x0, const float* __restrict__ bfi,
              float* __restrict__ out0,
              const int* __restrict__ b0, const int* __restrict__ n0i) {
  __shared__ unsigned short Bs[8192];   // 16 KB
  int g = blockIdx.x / 11, rem = blockIdx.x % 11;
  if (rem < 8) { fill_once(ei, counts, bucket, g * 8 + rem); return; }
  int o = g * 3 + rem - 8;
  if (o < 1000)
    gemm_tile<false, false, true, false>(x1, Wbf, nullptr, t_bf, o, nullptr, nullptr, Bs);
  else if (o < 1500)
    gemm_tile<true, false, false, true>(x0, Wbf + 16384, bfi, out0, o - 1000, b0, n0i, Bs);
}

// ---------------- aggregation (agg1): TWO rows per wave ----------------
template<bool OUTBF16, bool SEL>
__global__ __launch_bounds__(256)
void aggregate_k(const uint2* __restrict__ x,        // bf16 rows as 32 x uint2
                 const int* __restrict__ counts,
                 const unsigned int* __restrict__ bucket,  // rows of 32 uints
                 const float* __restrict__ bias, void* __restrict__ out_,
                 const int* __restrict__ bidx, const int* __restrict__ nidx) {
  int wave = (blockIdx.x * 256 + threadIdx.x) >> 6;
  int lane = threadIdx.x & 63;
  int l5   = lane & 31;
  int r    = wave * 2 + (lane >> 5);                 // my half's row
  int node = SEL ? (bidx[r] * ADJ_ + nidx[r]) : r;
  int cnt  = counts[node]; cnt = min(cnt, CAP);      // half-uniform
  unsigned int mp = bucket[node * 32 + l5];          // slots 2*l5, 2*l5+1

  float4 acc;
  if (bias) acc = ((const float4*)bias)[l5];
  else      acc = float4{0.f, 0.f, 0.f, 0.f};

#define SLOT_C(i)                                                            \
  ((int)((((unsigned int)__shfl((int)mp, ((i) >> 1) | (lane & 32), 64))      \
          >> (((i) & 1) * 16)) & 0xffffu))

  uint2 uu[AGUNROLL];
#pragma unroll
  for (int i = 0; i < AGUNROLL; i++)
    if (i < cnt) {                                   // half-uniform guard
      int s = SLOT_C(i);
      uu[i] = x[(size_t)s * 32 + l5];
    }
#pragma unroll
  for (int i = 0; i < AGUNROLL; i++)
    if (i < cnt) {
      acc.x += u2f(uu[i].x << 16);
      acc.y += u2f(uu[i].x & 0xffff0000u);
      acc.z += u2f(uu[i].y << 16);
      acc.w += u2f(uu[i].y & 0xffff0000u);
    }
  for (int d = AGUNROLL; d < cnt; d++) {             // rare tail (~2% of rows)
    unsigned int v = (unsigned int)__shfl((int)mp, (d >> 1) | (lane & 32), 64);
    int s = (int)((v >> ((d & 1) * 16)) & 0xffffu);
    uint2 u = x[(size_t)s * 32 + l5];
    acc.x += u2f(u.x << 16);
    acc.y += u2f(u.x & 0xffff0000u);
    acc.z += u2f(u.y << 16);
    acc.w += u2f(u.y & 0xffff0000u);
  }
#undef SLOT_C

  if (OUTBF16) {
    uint2 p; p.x = pack_bf2(acc.x, acc.y); p.y = pack_bf2(acc.z, acc.w);
    ((uint2*)out_)[(size_t)r * 32 + l5] = p;
  } else {
    ((float4*)out_)[(size_t)r * 32 + l5] = acc;
  }
}

// ---------------- aggmm: fused agg2 + br1 ----------------
// Block = 64 output rows, 4 waves x 16 rows. Lane (m=lane&15, q=lane>>4) owns
// dims {kc*32+q*8+j, j=0..7} of row rbase+wv*16+m — the MFMA A-frag layout.
// Gather loop: per slot i (to wave-max cnt), lane loads 4x uint4 bf16 segments
// of h1[src] and accumulates 32 f32. Then pack->af, stage Wc (frag bf16),
// 2x half MFMA, epilogue out1 = acc + bc[col] (f32).
__global__ __launch_bounds__(256)
void aggmm_k(const uint4* __restrict__ x,            // h1 rows as 16 x uint4
             const int* __restrict__ counts,
             const unsigned short* __restrict__ bucket,
             const unsigned short* __restrict__ WbfC,  // Wc frag bf16
             const float* __restrict__ bc, float* __restrict__ out1,
             const int* __restrict__ bidx, const int* __restrict__ nidx) {
  __shared__ unsigned short Bs[8192];   // 16 KB Wc staging
  int tid  = threadIdx.x;
  int lane = tid & 63;
  int wv   = tid >> 6;
  int m    = lane & 15;
  int q    = lane >> 4;
  int rbase = blockIdx.x * 64 + wv * 16;
  int r     = rbase + m;                             // my A-side row

  const short8v* Wv  = (const short8v*)WbfC;
  short8v*       Bsv = (short8v*)Bs;
  short8v w[4];
#pragma unroll
  for (int i = 0; i < 4; i++) w[i] = Wv[tid + i * 256];   // issue early (L2)

  int node = bidx[r] * ADJ_ + nidx[r];
  int cnt  = counts[node]; cnt = min(cnt, CAP);
  const unsigned short* brow = bucket + (size_t)node * CAP;

  // wave-max cnt (16-lane groups each contain all 16 m values)
  int maxc = cnt;
#pragma unroll
  for (int off = 1; off < 16; off <<= 1)
    maxc = max(maxc, __shfl_xor(maxc, off, 64));

  float acc[4][8];
#pragma unroll
  for (int kc = 0; kc < 4; kc++)
#pragma unroll
    for (int j = 0; j < 8; j++) acc[kc][j] = 0.f;

#define ACCU(kc, u) do {                                                \
    acc[kc][0] += u2f((u).x << 16); acc[kc][1] += u2f((u).x & 0xffff0000u); \
    acc[kc][2] += u2f((u).y << 16); acc[kc][3] += u2f((u).y & 0xffff0000u); \
    acc[kc][4] += u2f((u).z << 16); acc[kc][5] += u2f((u).z & 0xffff0000u); \
    acc[kc][6] += u2f((u).w << 16); acc[kc][7] += u2f((u).w & 0xffff0000u); \
  } while (0)

#pragma unroll 2
  for (int i = 0; i < maxc; i++) {
    if (i < cnt) {                                   // per-lane (m) guard
      int s = (int)brow[i];                          // L2-hot slot id
      const uint4* src = x + (size_t)s * 16 + q;
      uint4 u0 = src[0];
      uint4 u1 = src[4];
      uint4 u2 = src[8];
      uint4 u3 = src[12];
      ACCU(0, u0); ACCU(1, u1); ACCU(2, u2); ACCU(3, u3);
    }
  }
#undef ACCU

  // pack f32 accumulator -> bf16 A-frags (same rounding as old sel materialize)
  short8v af[4];
#pragma unroll
  for (int kc = 0; kc < 4; kc++) {
    union { short8v s; unsigned int u[4]; } t;
    t.u[0] = pack_bf2(acc[kc][0], acc[kc][1]);
    t.u[1] = pack_bf2(acc[kc][2], acc[kc][3]);
    t.u[2] = pack_bf2(acc[kc][4], acc[kc][5]);
    t.u[3] = pack_bf2(acc[kc][6], acc[kc][7]);
    af[kc] = t.s;
  }

#pragma unroll
  for (int i = 0; i < 4; i++) Bsv[tid + i * 256] = w[i];
  __syncthreads();

  float4v accm[8];
#pragma unroll
  for (int nb = 0; nb < 8; nb++) accm[nb] = (float4v){0.f, 0.f, 0.f, 0.f};

#pragma unroll
  for (int i = 0; i < 4; i++) w[i] = Wv[1024 + tid + i * 256];

#pragma unroll
  for (int nb = 0; nb < 4; nb++)
#pragma unroll
    for (int kc = 0; kc < 4; kc++) {
      short8v bf = Bsv[(nb * 4 + kc) * 64 + lane];
      accm[nb] = __builtin_amdgcn_mfma_f32_16x16x32_bf16(af[kc], bf, accm[nb], 0, 0, 0);
    }
  __syncthreads();
#pragma unroll
  for (int i = 0; i < 4; i++) Bsv[tid + i * 256] = w[i];
  __syncthreads();
#pragma unroll
  for (int nb = 4; nb < 8; nb++)
#pragma unroll
    for (int kc = 0; kc < 4; kc++) {
      short8v bf = Bsv[((nb - 4) * 4 + kc) * 64 + lane];
      accm[nb] = __builtin_amdgcn_mfma_f32_16x16x32_bf16(af[kc], bf, accm[nb], 0, 0, 0);
    }

#pragma unroll
  for (int nb = 0; nb < 8; nb++) {
    int col = nb * 16 + m;
    float bvn = bc[col];
#pragma unroll
    for (int i = 0; i < 4; i++) {
      int row = rbase + q * 4 + i;
      out1[(size_t)row * DV + col] = accm[nb][i] + bvn;
    }
  }
}

extern "C" void kernel_launch(void* const* d_in, const int* in_sizes, int n_in,
                              void* d_out, int out_size, void* d_ws, size_t ws_size,
                              hipStream_t stream) {
  const float* x0  = (const float*)d_in[0];
  const float* x1  = (const float*)d_in[1];
  const int*   ei  = (const int*)  d_in[2];
  const int*   b0  = (const int*)  d_in[3];
  const int*   n0i = (const int*)  d_in[4];
  const int*   b1  = (const int*)  d_in[5];
  const int*   n1i = (const int*)  d_in[6];
  const float* W1  = (const float*)d_in[7];
  const float* bb1 = (const float*)d_in[8];
  const float* W2  = (const float*)d_in[9];
  const float* bb2 = (const float*)d_in[10];
  const float* Wl  = (const float*)d_in[11];
  const float* bl  = (const float*)d_in[12];
  const float* Wfi = (const float*)d_in[13];
  const float* bfi = (const float*)d_in[14];
  float* out = (float*)d_out;

  // ws: t_bf 16MB | h_bf 16MB | counts 0.25MB | bucket 8MB | Wbf 96KB | bc 512B
  unsigned int*   t_bf   = (unsigned int*)d_ws;
  unsigned int*   h_bf   = t_bf + (size_t)N_ * 64;
  int*            counts = (int*)(h_bf + (size_t)N_ * 64);
  unsigned short* bucket = (unsigned short*)(counts + N_);
  unsigned short* Wbf    = bucket + (size_t)N_ * CAP;
  float*          bc     = (float*)(Wbf + 3 * 16384);

  // prep: counts=0, W1/Wfi frag, Wc=W2@Wl frag, bc=b2@Wl+bl
  prep_k<<<33, 256, 0, stream>>>(W1, Wfi, W2, Wl, bb2, bl, Wbf, bc, counts);

  // K1: wide single-pass fill ∪ t1=x1@W1 ∪ out0=gather(x0)@Wfi+bfi
  k1_fused<<<5632, 256, 0, stream>>>(ei, counts, bucket, x1, Wbf, t_bf,
                                     x0, bfi, out, b0, n0i);

  // h1 = A@t1 + b1  (bf16 out)  — 2 rows/wave
  aggregate_k<true, false><<<N_ / 8, 256, 0, stream>>>((const uint2*)t_bf, counts,
                                                       (const unsigned int*)bucket,
                                                       bb1, h_bf, nullptr, nullptr);
  // out1 = (A_sel@h1)@Wc + bc  — fused agg2+br1
  aggmm_k<<<M_ / 64, 256, 0, stream>>>((const uint4*)h_bf, counts, bucket,
                                       Wbf + 2 * 16384, bc, out + (size_t)M_ * DV,
                                       b1, n1i);
}